// Round 1
// baseline (1194.411 us; speedup 1.0000x reference)
//
#include <hip/hip_runtime.h>

// PlaneModel: B=8192 samples, NS=32 gathered voxels of P=64 feats each,
// tiny MLP 79->16 (LN, sum over NS) ->32 (LN) ->32 (LN,+skip) ->13 (tanh).
// All fp32 (no fp32 MFMA on CDNA4) -> vector ALU + HBM gather bound.
// Layout: 256-thread block = 8 samples; 32-lane group per sample; lane = pick.

#define NVX 8
#define PF 64
#define NSAMP 32
#define HID1 16
#define BASEW 32
#define OUTD 13
#define DIN 79
#define LN_EPS 1e-6f

__global__ __launch_bounds__(256, 4) void plane_kernel(
    const float* __restrict__ pos, const float* __restrict__ quat,
    const float* __restrict__ xz, const float* __restrict__ aabb,
    const int* __restrict__ widx, const float* __restrict__ pls,
    const float* __restrict__ w1, const float* __restrict__ b1,
    const float* __restrict__ g1, const float* __restrict__ be1,
    const float* __restrict__ w2a, const float* __restrict__ b2a,
    const float* __restrict__ g2a, const float* __restrict__ be2a,
    const float* __restrict__ w2b, const float* __restrict__ b2b,
    const float* __restrict__ g2b, const float* __restrict__ be2b,
    const float* __restrict__ wout, const float* __restrict__ bout,
    float* __restrict__ out)
{
    __shared__ __align__(16) float s_w1[DIN * HID1];      // 1264
    __shared__ __align__(16) float s_g1[HID1], s_be1[HID1];
    __shared__ __align__(16) float s_w2a[HID1 * BASEW];   // 512
    __shared__ __align__(16) float s_b2a[BASEW], s_g2a[BASEW], s_be2a[BASEW];
    __shared__ __align__(16) float s_w2b[BASEW * BASEW];  // 1024
    __shared__ __align__(16) float s_b2b[BASEW], s_g2b[BASEW], s_be2b[BASEW];
    __shared__ __align__(16) float s_wout[BASEW * OUTD];  // 416
    __shared__ __align__(16) float s_bout[OUTD + 3];
    __shared__ __align__(16) float s_posec[8][HID1];      // per-sample pose part of layer1 (incl b1)
    __shared__ __align__(16) float s_ex1[8][BASEW];
    __shared__ __align__(16) float s_ex2[8][BASEW];

    const int tid = threadIdx.x;

    // ---- stage weights into LDS (broadcast-read in hot loops) ----
    for (int i = tid; i < DIN * HID1; i += 256) s_w1[i] = w1[i];
    for (int i = tid; i < HID1 * BASEW; i += 256) s_w2a[i] = w2a[i];
    for (int i = tid; i < BASEW * BASEW; i += 256) s_w2b[i] = w2b[i];
    for (int i = tid; i < BASEW * OUTD; i += 256) s_wout[i] = wout[i];
    if (tid < HID1) { s_g1[tid] = g1[tid]; s_be1[tid] = be1[tid]; }
    if (tid < BASEW) {
        s_b2a[tid] = b2a[tid]; s_g2a[tid] = g2a[tid]; s_be2a[tid] = be2a[tid];
        s_b2b[tid] = b2b[tid]; s_g2b[tid] = g2b[tid]; s_be2b[tid] = be2b[tid];
    }
    if (tid < OUTD) s_bout[tid] = bout[tid];
    __syncthreads();

    const int g = tid >> 5;    // group (sample slot) 0..7
    const int r = tid & 31;    // lane within group = pick index / channel
    const int s = blockIdx.x * 8 + g;

    // ---- per-sample scalars (redundant per-lane, cheap; L1-cached) ----
    float q0 = quat[s * 4 + 0], q1 = quat[s * 4 + 1], q2 = quat[s * 4 + 2], q3 = quat[s * 4 + 3];
    float qn = rsqrtf(q0 * q0 + q1 * q1 + q2 * q2 + q3 * q3);
    float qx = q0 * qn, qy = q1 * qn, qz = q2 * qn, qw = q3 * qn;
    float R00 = 1.f - 2.f * (qy * qy + qz * qz), R01 = 2.f * (qx * qy - qz * qw), R02 = 2.f * (qx * qz + qy * qw);
    float R10 = 2.f * (qx * qy + qz * qw), R11 = 1.f - 2.f * (qx * qx + qz * qz), R12 = 2.f * (qy * qz - qx * qw);
    float R20 = 2.f * (qx * qz - qy * qw), R21 = 2.f * (qy * qz + qx * qw), R22 = 1.f - 2.f * (qx * qx + qy * qy);
    float p0 = pos[s * 3 + 0], p1 = pos[s * 3 + 1], p2 = pos[s * 3 + 2];
    float lo0 = aabb[s * 6 + 0], lo1 = aabb[s * 6 + 1], lo2 = aabb[s * 6 + 2];
    float hi0 = aabb[s * 6 + 3], hi1 = aabb[s * 6 + 4], hi2 = aabb[s * 6 + 5];
    float scale = __expf(pls[0]);

    // ---- per-sample pose-part of layer1 (same for all 32 picks): lanes r<16 ----
    if (r < HID1) {
        float pose[12] = {p0 * scale, p1 * scale, p2 * scale,
                          R00, R01, R02, R10, R11, R12, R20, R21, R22};
        float a = b1[r];
#pragma unroll
        for (int t = 0; t < 12; ++t) a += pose[t] * s_w1[(67 + t) * HID1 + r];
        s_posec[g][r] = a;
    }
    __syncthreads();

    // ---- layer 1: row = pick r ----
    int wv = widx[s * NSAMP + r];
    float vx = ((float)(wv >> 6) + 0.5f) * 0.125f * (hi0 - lo0) + lo0;
    float vy = ((float)((wv >> 3) & 7) + 0.5f) * 0.125f * (hi1 - lo1) + lo1;
    float vz = ((float)(wv & 7) + 0.5f) * 0.125f * (hi2 - lo2) + lo2;
    float px = R00 * vx + R01 * vy + R02 * vz + p0;
    float py = R10 * vx + R11 * vy + R12 * vz + p1;
    float pz = R20 * vx + R21 * vy + R22 * vz + p2;

    const float4* w1v = (const float4*)s_w1;   // row d -> w1v[d*4 + q]
    float acc[16];
#pragma unroll
    for (int q = 0; q < 4; ++q) {
        float4 a = ((const float4*)&s_posec[g][0])[q];
        float4 wa = w1v[0 * 4 + q], wb = w1v[1 * 4 + q], wc = w1v[2 * 4 + q];
        acc[4 * q + 0] = a.x + px * wa.x + py * wb.x + pz * wc.x;
        acc[4 * q + 1] = a.y + px * wa.y + py * wb.y + pz * wc.y;
        acc[4 * q + 2] = a.z + px * wa.z + py * wb.z + pz * wc.z;
        acc[4 * q + 3] = a.w + px * wa.w + py * wb.w + pz * wc.w;
    }

    // gather: 256B contiguous per voxel, 16 x float4
    const float4* zp = (const float4*)(xz + ((long long)s * 512 + wv) * (long long)PF);
#pragma unroll 4
    for (int ch = 0; ch < 16; ++ch) {
        float4 zv = zp[ch];
        float zs[4] = {zv.x, zv.y, zv.z, zv.w};
        const int d0 = 3 + ch * 4;
#pragma unroll
        for (int t = 0; t < 4; ++t) {
#pragma unroll
            for (int q = 0; q < 4; ++q) {
                float4 wq = w1v[(d0 + t) * 4 + q];   // wave-uniform -> LDS broadcast
                acc[4 * q + 0] += zs[t] * wq.x;
                acc[4 * q + 1] += zs[t] * wq.y;
                acc[4 * q + 2] += zs[t] * wq.z;
                acc[4 * q + 3] += zs[t] * wq.w;
            }
        }
    }

    // relu + LN over 16 (in-registers)
    float m = 0.f;
#pragma unroll
    for (int c = 0; c < 16; ++c) { acc[c] = fmaxf(acc[c], 0.f); m += acc[c]; }
    m *= (1.f / 16.f);
    float var = 0.f;
#pragma unroll
    for (int c = 0; c < 16; ++c) { float d = acc[c] - m; var += d * d; }
    var *= (1.f / 16.f);
    float inv = rsqrtf(var + LN_EPS);
    float o[16];
#pragma unroll
    for (int c = 0; c < 16; ++c) o[c] = (acc[c] - m) * inv * s_g1[c] + s_be1[c];

    // z = 2 * sum over 32 picks: butterfly within the 32-lane group
#pragma unroll
    for (int c = 0; c < 16; ++c) {
        float t = o[c];
        t += __shfl_xor(t, 1);
        t += __shfl_xor(t, 2);
        t += __shfl_xor(t, 4);
        t += __shfl_xor(t, 8);
        t += __shfl_xor(t, 16);
        o[c] = 2.f * t;            // every lane now holds full z16
    }

    // ---- layer 2a: lane r = channel ----
    float a2 = s_b2a[r];
#pragma unroll
    for (int k = 0; k < 16; ++k) a2 += o[k] * s_w2a[k * BASEW + r];  // bank = r, conflict-free
    a2 = fmaxf(a2, 0.f);
    float s1 = a2, s2 = a2 * a2;
#pragma unroll
    for (int mk = 1; mk <= 16; mk <<= 1) { s1 += __shfl_xor(s1, mk); s2 += __shfl_xor(s2, mk); }
    float mean = s1 * (1.f / 32.f);
    float v2 = s2 * (1.f / 32.f) - mean * mean;
    float skip = (a2 - mean) * rsqrtf(v2 + LN_EPS) * s_g2a[r] + s_be2a[r];

    s_ex1[g][r] = skip;
    __syncthreads();

    // ---- layer 2b ----
    float a3 = s_b2b[r];
    const float4* ex1v = (const float4*)&s_ex1[g][0];
#pragma unroll
    for (int kq = 0; kq < 8; ++kq) {
        float4 e = ex1v[kq];
        int k = kq * 4;
        a3 += e.x * s_w2b[(k + 0) * BASEW + r] + e.y * s_w2b[(k + 1) * BASEW + r]
            + e.z * s_w2b[(k + 2) * BASEW + r] + e.w * s_w2b[(k + 3) * BASEW + r];
    }
    a3 = fmaxf(a3, 0.f);
    s1 = a3; s2 = a3 * a3;
#pragma unroll
    for (int mk = 1; mk <= 16; mk <<= 1) { s1 += __shfl_xor(s1, mk); s2 += __shfl_xor(s2, mk); }
    mean = s1 * (1.f / 32.f);
    v2 = s2 * (1.f / 32.f) - mean * mean;
    float zf = (a3 - mean) * rsqrtf(v2 + LN_EPS) * s_g2b[r] + s_be2b[r] + skip;

    s_ex2[g][r] = zf;
    __syncthreads();

    // ---- output layer: lanes r<13 ----
    if (r < OUTD) {
        float a4 = s_bout[r];
        const float4* ex2v = (const float4*)&s_ex2[g][0];
#pragma unroll
        for (int kq = 0; kq < 8; ++kq) {
            float4 e = ex2v[kq];
            int k = kq * 4;
            a4 += e.x * s_wout[(k + 0) * OUTD + r] + e.y * s_wout[(k + 1) * OUTD + r]
                + e.z * s_wout[(k + 2) * OUTD + r] + e.w * s_wout[(k + 3) * OUTD + r];
        }
        float ex = __expf(2.f * a4);
        out[s * OUTD + r] = 1.f - 2.f / (ex + 1.f);
    }
}

extern "C" void kernel_launch(void* const* d_in, const int* in_sizes, int n_in,
                              void* d_out, int out_size, void* d_ws, size_t ws_size,
                              hipStream_t stream) {
    const float* pos  = (const float*)d_in[0];
    const float* quat = (const float*)d_in[1];
    const float* xz   = (const float*)d_in[2];
    const float* aabb = (const float*)d_in[3];
    const int*   widx = (const int*)d_in[4];
    const float* pls  = (const float*)d_in[5];
    const float* w1   = (const float*)d_in[6];
    const float* b1   = (const float*)d_in[7];
    const float* g1   = (const float*)d_in[8];
    const float* be1  = (const float*)d_in[9];
    const float* w2a  = (const float*)d_in[10];
    const float* b2a  = (const float*)d_in[11];
    const float* g2a  = (const float*)d_in[12];
    const float* be2a = (const float*)d_in[13];
    const float* w2b  = (const float*)d_in[14];
    const float* b2b  = (const float*)d_in[15];
    const float* g2b  = (const float*)d_in[16];
    const float* be2b = (const float*)d_in[17];
    const float* wout = (const float*)d_in[18];
    const float* bout = (const float*)d_in[19];
    float* out = (float*)d_out;

    dim3 grid(8192 / 8), block(256);
    hipLaunchKernelGGL(plane_kernel, grid, block, 0, stream,
                       pos, quat, xz, aabb, widx, pls,
                       w1, b1, g1, be1, w2a, b2a, g2a, be2a,
                       w2b, b2b, g2b, be2b, wout, bout, out);
}